// Round 15
// baseline (225.736 us; speedup 1.0000x reference)
//
#include <hip/hip_runtime.h>
#include <math.h>

// GraphRespiratory: 2-layer GAT (edge features, concat=False) + factor graph.
// N=50000, E=800000, IN=128, HID=OUT=64, H=2, NC=5, EC=2, NUM_ITER=2, GAMMA=1.
//
// R14 changes vs R13 (latency/MLP round):
//  - k_gat_pull phase B: 8-deep batches, all 8 uint4 gathers issued upfront
//    (was 2-deep) -> 4x memory-level parallelism in the latency-bound gather.
//  - dstnbr (src-id, 4B) emitted by k_bkt_sort: fg kernels' dst-side walk
//    becomes dense stride-4 (was stride-8 int2 reading only .x).
//  - k_fg_final edge part: 2 edges/thread, batched loads (4 gathers in flight).

static inline int cdiv_i(long long a, long long b) { return (int)((a + b - 1) / b); }

#define BSH 8           // bucket shift: 256 nodes per bucket
#define CBK 8           // edges per thread in bucket scatter (2048/block)

typedef __attribute__((ext_vector_type(8))) short bf16x8s;
typedef __attribute__((ext_vector_type(4))) float f32x4;

__device__ __forceinline__ float fexp(float x) {
  return __builtin_amdgcn_exp2f(x * 1.44269504088896f);
}
__device__ __forceinline__ float flog(float x) {
  return __builtin_amdgcn_logf(x) * 0.693147180559945f;
}
__device__ __forceinline__ float frcp(float x) {
  return __builtin_amdgcn_rcpf(x);
}

__device__ __forceinline__ unsigned short bf16r(float x) {
  unsigned u = __float_as_uint(x);
  return (unsigned short)((u + 0x7fffu + ((u >> 16) & 1u)) >> 16);
}
__device__ __forceinline__ unsigned pack_bf2(float a, float b) {
  unsigned ua = __float_as_uint(a), ub = __float_as_uint(b);
  unsigned ra = (ua + 0x7fffu + ((ua >> 16) & 1u)) >> 16;
  unsigned rb = (ub + 0x7fffu + ((ub >> 16) & 1u)) & 0xffff0000u;
  return ra | rb;
}
__device__ __forceinline__ float bf_lo(unsigned v) { return __uint_as_float(v << 16); }
__device__ __forceinline__ float bf_hi(unsigned v) { return __uint_as_float(v & 0xffff0000u); }

// Merged prep (ONE block): zero bucket cursors; consts; wext (LDS); wfrag.
// consts: [0..3] w_e1[h][k], [4..7] w_e2[h][k], [8] avg_ef, [9] avg_nf, [10] dbec
// wf layout: [K/32][9][64 lanes][8 j]; element = W[kc+(lane>>4)*8+j][ct*16+(lane&15)]
__global__ __launch_bounds__(256)
void k_prep(const float* __restrict__ W1, const float* __restrict__ as1,
            const float* __restrict__ ad1, const float* __restrict__ atte1,
            const float* __restrict__ We1,
            const float* __restrict__ W2, const float* __restrict__ as2,
            const float* __restrict__ ad2, const float* __restrict__ atte2,
            const float* __restrict__ We2,
            const float* __restrict__ node_fw, const float* __restrict__ edge_fw,
            const float* __restrict__ bec, float* __restrict__ consts,
            unsigned short* __restrict__ wf1, unsigned short* __restrict__ wf2,
            int* __restrict__ cur_d, int* __restrict__ cur_s) {
  __shared__ float wext1[128 * 4], wext2[64 * 4];
  int t = threadIdx.x;
  cur_d[t] = 0; cur_s[t] = 0;
  if (t == 0) {
    for (int h = 0; h < 2; ++h)
      for (int k = 0; k < 2; ++k) {
        float s1 = 0.f, s2 = 0.f;
        for (int c = 0; c < 64; ++c) {
          s1 += We1[k * 128 + h * 64 + c] * atte1[h * 64 + c];
          s2 += We2[k * 128 + h * 64 + c] * atte2[h * 64 + c];
        }
        consts[h * 2 + k] = s1;
        consts[4 + h * 2 + k] = s2;
      }
    float ef = 0.f;                    // edge_fw is [EC=2, NC=5]; mean of [1:,1:]
    for (int j = 1; j < 5; ++j) ef += edge_fw[5 + j];
    consts[8] = ef * 0.25f;
    float nf = 0.f;                    // node_fw is [NC=5, EC=2]; mean of [1:,1:]
    for (int i = 1; i < 5; ++i) nf += node_fw[i * 2 + 1];
    consts[9] = nf * 0.25f;
    consts[10] = bec[1] - bec[0];
  }
  for (int o = t; o < 128 * 4; o += 256) {
    int k = o >> 2, j = o & 3;
    const float* att = (j < 2 ? as1 : ad1) + (j & 1) * 64;
    const float* wr = W1 + k * 128 + (j & 1) * 64;
    float s = 0.f;
    for (int c = 0; c < 64; ++c) s += wr[c] * att[c];
    wext1[o] = s;
  }
  for (int o = t; o < 64 * 4; o += 256) {
    int k = o >> 2, j = o & 3;
    const float* att = (j < 2 ? as2 : ad2) + (j & 1) * 64;
    const float* wr = W2 + k * 128 + (j & 1) * 64;
    float s = 0.f;
    for (int c = 0; c < 64; ++c) s += wr[c] * att[c];
    wext2[o] = s;
  }
  __syncthreads();
  for (int o = t; o < 4 * 9 * 512; o += 256) {       // K=128
    int kc = o / (9 * 512), rem = o % (9 * 512);
    int ct = rem / 512, li = rem % 512;
    int lane = li >> 3, j = li & 7;
    int k = kc * 32 + ((lane >> 4) << 3) + j, c = lane & 15;
    float v = (ct < 8) ? W1[k * 128 + ct * 16 + c] : (c < 4 ? wext1[k * 4 + c] : 0.f);
    wf1[o] = bf16r(v);
  }
  for (int o = t; o < 2 * 9 * 512; o += 256) {       // K=64
    int kc = o / (9 * 512), rem = o % (9 * 512);
    int ct = rem / 512, li = rem % 512;
    int lane = li >> 3, j = li & 7;
    int k = kc * 32 + ((lane >> 4) << 3) + j, c = lane & 15;
    float v = (ct < 8) ? W2[k * 128 + ct * 16 + c] : (c < 4 ? wext2[k * 4 + c] : 0.f);
    wf2[o] = bf16r(v);
  }
}

// ---- bucketed CSR build ----
__global__ void k_bkt_hist(const int* __restrict__ src, const int* __restrict__ dst,
                           int* __restrict__ hist_d, int* __restrict__ hist_s,
                           int nbkt, int E) {
  __shared__ int hd[256], hs[256];
  int t = threadIdx.x;
  hd[t] = 0; hs[t] = 0;
  __syncthreads();
  for (int e = blockIdx.x * blockDim.x + t; e < E; e += gridDim.x * blockDim.x) {
    atomicAdd(&hd[dst[e] >> BSH], 1);
    atomicAdd(&hs[src[e] >> BSH], 1);
  }
  __syncthreads();
  if (t < nbkt) {
    if (hd[t]) atomicAdd(&hist_d[t], hd[t]);
    if (hs[t]) atomicAdd(&hist_s[t], hs[t]);
  }
}

// one block: exclusive-scan both histograms -> bases (nbkt+1) and cursors (in place)
__global__ void k_bkt_scan(int* __restrict__ cur_d, int* __restrict__ base_d,
                           int* __restrict__ cur_s, int* __restrict__ base_s, int nbkt) {
  __shared__ int l[256];
  int t = threadIdx.x;
  int v = (t < nbkt) ? cur_d[t] : 0;
  l[t] = v; __syncthreads();
  for (int off = 1; off < 256; off <<= 1) {
    int x = (t >= off) ? l[t - off] : 0; __syncthreads();
    l[t] += x; __syncthreads();
  }
  int incl = l[t];
  if (t < nbkt) { base_d[t] = incl - v; cur_d[t] = incl - v; }
  if (t == nbkt - 1) base_d[nbkt] = incl;
  __syncthreads();
  v = (t < nbkt) ? cur_s[t] : 0;
  l[t] = v; __syncthreads();
  for (int off = 1; off < 256; off <<= 1) {
    int x = (t >= off) ? l[t - off] : 0; __syncthreads();
    l[t] += x; __syncthreads();
  }
  incl = l[t];
  if (t < nbkt) { base_s[t] = incl - v; cur_s[t] = incl - v; }
  if (t == nbkt - 1) base_s[nbkt] = incl;
}

// block-staged bucket scatter: 2048 edges/block in regs; LDS per-bucket counts;
// one global atomicAdd per (bucket,block) to reserve; chunky tail writes.
__global__ __launch_bounds__(256)
void k_bkt_scatter(const int* __restrict__ src, const int* __restrict__ dst,
                   const float* __restrict__ eattr2,
                   int* __restrict__ cur_d, int* __restrict__ cur_s,
                   int4* __restrict__ stage_d, int2* __restrict__ stage_s,
                   int nbkt, int E) {
  __shared__ int cd[256], cs[256], bd[256], bs[256];
  int t = threadIdx.x;
  cd[t] = 0; cs[t] = 0;
  __syncthreads();
  int base = blockIdx.x * 256 * CBK;
  int s[CBK], d[CBK]; unsigned ep[CBK];
#pragma unroll
  for (int c = 0; c < CBK; ++c) {
    int e = base + c * 256 + t;
    if (e < E) {
      s[c] = src[e]; d[c] = dst[e];
      float2 ev = *(const float2*)&eattr2[2 * e];
      ep[c] = pack_bf2(ev.x, ev.y);
      atomicAdd(&cd[d[c] >> BSH], 1);
      atomicAdd(&cs[s[c] >> BSH], 1);
    } else s[c] = -1;
  }
  __syncthreads();
  if (t < nbkt) {
    bd[t] = cd[t] ? atomicAdd(&cur_d[t], cd[t]) : 0;
    bs[t] = cs[t] ? atomicAdd(&cur_s[t], cs[t]) : 0;
    cd[t] = 0; cs[t] = 0;
  }
  __syncthreads();
#pragma unroll
  for (int c = 0; c < CBK; ++c) {
    if (s[c] < 0) continue;
    int db = d[c] >> BSH, sb = s[c] >> BSH;
    int pos = bd[db] + atomicAdd(&cd[db], 1);
    stage_d[pos] = make_int4(s[c], d[c], (int)ep[c], 0);
    int pos2 = bs[sb] + atomicAdd(&cs[sb], 1);
    stage_s[pos2] = make_int2(s[c], d[c]);
  }
}

// merged per-bucket counting sorts: blocks [0,nbkt) dst side, [nbkt,2nbkt) src.
// dst side also emits dstnbr (src-id only, dense 4B) for the fg kernels.
__global__ __launch_bounds__(256)
void k_bkt_sort(const int4* __restrict__ stage_d, const int* __restrict__ base_d,
                int* __restrict__ rowptr_d, int2* __restrict__ rec,
                int* __restrict__ dstnbr,
                const int2* __restrict__ stage_s, const int* __restrict__ base_s,
                int* __restrict__ rowptr_s, int* __restrict__ srcnbr,
                int N, int nbkt) {
  int t = threadIdx.x;
  __shared__ int cnt[256], cur[256], l[256];
  if ((int)blockIdx.x < nbkt) {
    int b = blockIdx.x;
    int nlo = b << BSH;
    int b0 = base_d[b], b1 = base_d[b + 1];
    cnt[t] = 0;
    __syncthreads();
    for (int j = b0 + t; j < b1; j += 256)
      atomicAdd(&cnt[stage_d[j].y - nlo], 1);
    __syncthreads();
    int v = cnt[t];
    l[t] = v; __syncthreads();
    for (int off = 1; off < 256; off <<= 1) {
      int x = (t >= off) ? l[t - off] : 0; __syncthreads();
      l[t] += x; __syncthreads();
    }
    int excl = l[t] - v;
    if (nlo + t < N) rowptr_d[nlo + t] = b0 + excl;
    cur[t] = excl;
    __syncthreads();
    for (int j = b0 + t; j < b1; j += 256) {
      int4 r = stage_d[j];
      int pos = b0 + atomicAdd(&cur[r.y - nlo], 1);
      rec[pos] = make_int2(r.x, r.z);
      dstnbr[pos] = r.x;
    }
  } else {
    int b = blockIdx.x - nbkt;
    int nlo = b << BSH;
    int b0 = base_s[b], b1 = base_s[b + 1];
    cnt[t] = 0;
    __syncthreads();
    for (int j = b0 + t; j < b1; j += 256)
      atomicAdd(&cnt[stage_s[j].x - nlo], 1);
    __syncthreads();
    int v = cnt[t];
    l[t] = v; __syncthreads();
    for (int off = 1; off < 256; off <<= 1) {
      int x = (t >= off) ? l[t - off] : 0; __syncthreads();
      l[t] += x; __syncthreads();
    }
    int excl = l[t] - v;
    if (nlo + t < N) rowptr_s[nlo + t] = b0 + excl;
    cur[t] = excl;
    __syncthreads();
    for (int j = b0 + t; j < b1; j += 256) {
      int2 r = stage_s[j];
      int pos = b0 + atomicAdd(&cur[r.x - nlo], 1);
      srcnbr[pos] = r.y;
    }
  }
}

// MFMA GEMM + attention columns. A[N][K] f32 -> bf16 in-reg; Wf pre-swizzled
// B-fragments (9 col-tiles: 8 of W + 1 of wext). Block = 4 waves x 16 rows.
template<int K>
__global__ __launch_bounds__(256)
void k_gemm_att_mfma(const float* __restrict__ A, const unsigned short* __restrict__ Wf,
                     unsigned* __restrict__ h16, float* __restrict__ asd, int N) {
  int wv = threadIdx.x >> 6, lane = threadIdx.x & 63;
  int r0 = blockIdx.x * 64 + wv * 16;
  int arow = r0 + (lane & 15);
  int kbase = (lane >> 4) * 8;
  f32x4 acc[9];
#pragma unroll
  for (int ct = 0; ct < 9; ++ct) acc[ct] = (f32x4){0.f, 0.f, 0.f, 0.f};

#pragma unroll
  for (int kc = 0; kc < K; kc += 32) {
    float4 v0 = make_float4(0.f, 0.f, 0.f, 0.f);
    float4 v1 = make_float4(0.f, 0.f, 0.f, 0.f);
    if (arow < N) {
      const float* ap = A + (long long)arow * K + kc + kbase;
      v0 = *(const float4*)ap;
      v1 = *(const float4*)(ap + 4);
    }
    bf16x8s a;
    a[0] = (short)bf16r(v0.x); a[1] = (short)bf16r(v0.y);
    a[2] = (short)bf16r(v0.z); a[3] = (short)bf16r(v0.w);
    a[4] = (short)bf16r(v1.x); a[5] = (short)bf16r(v1.y);
    a[6] = (short)bf16r(v1.z); a[7] = (short)bf16r(v1.w);
    const unsigned short* wp = Wf + (size_t)(kc >> 5) * 9 * 512 + lane * 8;
#pragma unroll
    for (int ct = 0; ct < 9; ++ct) {
      bf16x8s b = *(const bf16x8s*)(wp + ct * 512);
      acc[ct] = __builtin_amdgcn_mfma_f32_16x16x32_bf16(a, b, acc[ct], 0, 0, 0);
    }
  }
  // D layout: col = lane&15, row = (lane>>4)*4 + reg
  int c = lane & 15;
  int orow = r0 + (lane >> 4) * 4;
#pragma unroll
  for (int r = 0; r < 4; ++r) {
    int gr = orow + r;
    if (gr >= N) continue;
#pragma unroll
    for (int ct = 0; ct < 4; ++ct)
      h16[((long long)gr << 6) | (ct * 16 + c)] = pack_bf2(acc[ct][r], acc[ct + 4][r]);
    if (c < 4) asd[gr * 4 + c] = acc[8][r];
  }
}

// Fused GAT edge phase, pull-mode. ONE 16-LANE GROUP PER DST NODE (4/wave).
// Phase B: 8-deep batches, all 8 uint4 gathers issued before the FMAs.
template<bool RELU, bool HEAD>
__global__ __launch_bounds__(256)
void k_gat_pull(const int* __restrict__ rowptr, const int2* __restrict__ rec,
                const float* __restrict__ asd, const unsigned* __restrict__ h16,
                const float* __restrict__ we, const float* __restrict__ bias,
                const float* __restrict__ Wn, const float* __restrict__ bn,
                const float* __restrict__ Wec,
                float* __restrict__ out, float* __restrict__ p_n,
                int2* __restrict__ fgn8, int N, int E) {
  __shared__ int2 ed[4][64];
  int wv = threadIdx.x >> 6, lane = threadIdx.x & 63;
  int g = lane >> 4;        // group (node) within wave
  int tl = lane & 15;       // lane within group = col-quad index
  int d = blockIdx.x * 16 + wv * 4 + g;
  if (d >= N) return;       // whole group exits together (shfl stays in-group)
  int r0 = rowptr[d];
  int r1 = (d + 1 < N) ? rowptr[d + 1] : E;
  int deg = r1 - r0;
  float4 Ad = *(const float4*)&asd[4 * d];
  float w0 = we[0], w1 = we[1], w2 = we[2], w3 = we[3];
  float den0 = 0.f, den1 = 0.f, se0 = 0.f, se1 = 0.f;
  float accA[4] = {0.f, 0.f, 0.f, 0.f}, accB[4] = {0.f, 0.f, 0.f, 0.f};
  int2* edg = &ed[wv][g << 4];
  for (int cb = 0; cb < deg; cb += 16) {
    int j = cb + tl;
    int s = 0; unsigned eapk = 0;
    if (j < deg) {
      int2 rc = rec[r0 + j];
      s = rc.x;
      unsigned ep = (unsigned)rc.y;
      float e0 = bf_lo(ep), e1 = bf_hi(ep);
      float4 As = *(const float4*)&asd[4 * s];
      float x0 = As.x + Ad.z + e0 * w0 + e1 * w1;
      float x1 = As.y + Ad.w + e0 * w2 + e1 * w3;
      x0 = x0 >= 0.f ? x0 : 0.2f * x0;
      x1 = x1 >= 0.f ? x1 : 0.2f * x1;
      float ea0 = fexp(x0), ea1 = fexp(x1);
      eapk = pack_bf2(ea0, ea1);
      den0 += ea0; den1 += ea1; se0 += e0; se1 += e1;
    }
    edg[tl] = make_int2(s, (int)eapk);   // same-wave LDS: no barrier needed
    int m = min(16, deg - cb);
    int j2 = 0;
    for (; j2 + 8 <= m; j2 += 8) {       // 8 gathers in flight
      int2 v[8]; uint4 q[8];
#pragma unroll
      for (int u = 0; u < 8; ++u) v[u] = edg[j2 + u];
#pragma unroll
      for (int u = 0; u < 8; ++u)
        q[u] = *(const uint4*)&h16[((long long)v[u].x << 6) | (tl << 2)];
#pragma unroll
      for (int u = 0; u < 8; ++u) {
        float a0 = bf_lo((unsigned)v[u].y), a1 = bf_hi((unsigned)v[u].y);
        accA[0] += a0 * bf_lo(q[u].x); accB[0] += a1 * bf_hi(q[u].x);
        accA[1] += a0 * bf_lo(q[u].y); accB[1] += a1 * bf_hi(q[u].y);
        accA[2] += a0 * bf_lo(q[u].z); accB[2] += a1 * bf_hi(q[u].z);
        accA[3] += a0 * bf_lo(q[u].w); accB[3] += a1 * bf_hi(q[u].w);
      }
    }
    if (j2 + 4 <= m) {                   // 4-batch
      int2 v[4]; uint4 q[4];
#pragma unroll
      for (int u = 0; u < 4; ++u) v[u] = edg[j2 + u];
#pragma unroll
      for (int u = 0; u < 4; ++u)
        q[u] = *(const uint4*)&h16[((long long)v[u].x << 6) | (tl << 2)];
#pragma unroll
      for (int u = 0; u < 4; ++u) {
        float a0 = bf_lo((unsigned)v[u].y), a1 = bf_hi((unsigned)v[u].y);
        accA[0] += a0 * bf_lo(q[u].x); accB[0] += a1 * bf_hi(q[u].x);
        accA[1] += a0 * bf_lo(q[u].y); accB[1] += a1 * bf_hi(q[u].y);
        accA[2] += a0 * bf_lo(q[u].z); accB[2] += a1 * bf_hi(q[u].z);
        accA[3] += a0 * bf_lo(q[u].w); accB[3] += a1 * bf_hi(q[u].w);
      }
      j2 += 4;
    }
    for (; j2 < m; ++j2) {
      int2 va = edg[j2];
      uint4 qa = *(const uint4*)&h16[((long long)va.x << 6) | (tl << 2)];
      float a0 = bf_lo((unsigned)va.y), a1 = bf_hi((unsigned)va.y);
      accA[0] += a0 * bf_lo(qa.x); accB[0] += a1 * bf_hi(qa.x);
      accA[1] += a0 * bf_lo(qa.y); accB[1] += a1 * bf_hi(qa.y);
      accA[2] += a0 * bf_lo(qa.z); accB[2] += a1 * bf_hi(qa.z);
      accA[3] += a0 * bf_lo(qa.w); accB[3] += a1 * bf_hi(qa.w);
    }
  }
  // reduce den/se within the 16-lane group
  for (int off = 8; off; off >>= 1) {
    den0 += __shfl_xor(den0, off); den1 += __shfl_xor(den1, off);
    se0  += __shfl_xor(se0, off);  se1  += __shfl_xor(se1, off);
  }
  // self-loop (identical on all 16 lanes)
  float id = frcp(fmaxf((float)deg, 1.0f));
  float le0 = se0 * id, le1 = se1 * id;
  float x0 = Ad.x + Ad.z + le0 * w0 + le1 * w1;
  float x1 = Ad.y + Ad.w + le0 * w2 + le1 * w3;
  x0 = x0 >= 0.f ? x0 : 0.2f * x0;
  x1 = x1 >= 0.f ? x1 : 0.2f * x1;
  float eas0 = fexp(x0), eas1 = fexp(x1);
  den0 += eas0; den1 += eas1;
  uint4 qd = *(const uint4*)&h16[((long long)d << 6) | (tl << 2)];
  accA[0] += eas0 * bf_lo(qd.x); accB[0] += eas1 * bf_hi(qd.x);
  accA[1] += eas0 * bf_lo(qd.y); accB[1] += eas1 * bf_hi(qd.y);
  accA[2] += eas0 * bf_lo(qd.z); accB[2] += eas1 * bf_hi(qd.z);
  accA[3] += eas0 * bf_lo(qd.w); accB[3] += eas1 * bf_hi(qd.w);
  float rcp0 = frcp(den0 + 1e-16f), rcp1 = frcp(den1 + 1e-16f);
  float4 bs = *(const float4*)&bias[tl << 2];
  float v0 = 0.5f * (accA[0] * rcp0 + accB[0] * rcp1) + bs.x;
  float v1 = 0.5f * (accA[1] * rcp0 + accB[1] * rcp1) + bs.y;
  float v2 = 0.5f * (accA[2] * rcp0 + accB[2] * rcp1) + bs.z;
  float v3 = 0.5f * (accA[3] * rcp0 + accB[3] * rcp1) + bs.w;
  if (HEAD) {
    int c0 = tl << 2;
    float pv[7];
#pragma unroll
    for (int j = 0; j < 5; ++j)
      pv[j] = v0 * Wn[c0 * 5 + j] + v1 * Wn[(c0 + 1) * 5 + j]
            + v2 * Wn[(c0 + 2) * 5 + j] + v3 * Wn[(c0 + 3) * 5 + j];
    pv[5] = v0 * Wec[c0 * 2] + v1 * Wec[(c0 + 1) * 2]
          + v2 * Wec[(c0 + 2) * 2] + v3 * Wec[(c0 + 3) * 2];
    pv[6] = v0 * Wec[c0 * 2 + 1] + v1 * Wec[(c0 + 1) * 2 + 1]
          + v2 * Wec[(c0 + 2) * 2 + 1] + v3 * Wec[(c0 + 3) * 2 + 1];
    for (int off = 8; off; off >>= 1) {
#pragma unroll
      for (int j = 0; j < 7; ++j) pv[j] += __shfl_xor(pv[j], off);
    }
    if (tl == 0) {
      float l[5]; float m = -1e30f;
#pragma unroll
      for (int j = 0; j < 5; ++j) { l[j] = pv[j] + bn[j]; m = fmaxf(m, l[j]); }
      float ssum = 0.f;
#pragma unroll
      for (int j = 0; j < 5; ++j) { l[j] = fexp(l[j] - m); ssum += l[j]; }
      float inv = frcp(ssum);
#pragma unroll
      for (int j = 0; j < 5; ++j) p_n[5 * d + j] = l[j] * inv;
      float nab0 = (ssum - l[0]) * inv;
      fgn8[d] = make_int2(__float_as_int(pv[6] - pv[5]), (int)pack_bf2(nab0, 0.f));
    }
  } else {
    if (RELU) {
      v0 = fmaxf(v0, 0.f); v1 = fmaxf(v1, 0.f);
      v2 = fmaxf(v2, 0.f); v3 = fmaxf(v3, 0.f);
    }
    *(float4*)&out[(long long)d * 64 + (tl << 2)] = make_float4(v0, v1, v2, v3);
  }
}

// eab = c / (c + exp(-t)) : one rcp, shared structure.
__device__ __forceinline__ float fg_eab(float t, float c) {
  return c * frcp(c + fexp(-t));
}

// factor-graph node-pull iteration 1. FOUR LANES PER NODE (stride-4 edge split).
__global__ void k_fg_pull1(const int* __restrict__ rowptr_d, const int* __restrict__ dstnbr,
                           const int* __restrict__ rowptr_s, const int* __restrict__ srcnbr,
                           float* __restrict__ p_n, int2* __restrict__ fgn8,
                           const float* __restrict__ consts, int N, int E) {
  int gid = blockIdx.x * blockDim.x + threadIdx.x;
  int n = gid >> 2, q = gid & 3;
  if (n >= N) return;
  int2 F = fgn8[n];
  float qv = __uint_as_float((unsigned)F.x);
  float nab0 = bf_lo((unsigned)F.y);
  float avg_ef = consts[8], avg_nf = consts[9], dbec = consts[10];
  int rd0 = rowptr_d[n], rd1 = (n + 1 < N) ? rowptr_d[n + 1] : E;
  int rs0 = rowptr_s[n], rs1 = (n + 1 < N) ? rowptr_s[n + 1] : E;
  float s_eab = 0.f;
  for (int j = rd0 + q; j < rd1; j += 4) {
    int2 Fo = fgn8[dstnbr[j]];
    float t = 0.5f * (qv + __uint_as_float((unsigned)Fo.x)) + dbec;
    float c = 1.0f + fmaxf(nab0, bf_lo((unsigned)Fo.y)) * avg_ef;
    s_eab += fg_eab(t, c);
  }
  for (int j = rs0 + q; j < rs1; j += 4) {
    int2 Fo = fgn8[srcnbr[j]];
    float t = 0.5f * (qv + __uint_as_float((unsigned)Fo.x)) + dbec;
    float c = 1.0f + fmaxf(nab0, bf_lo((unsigned)Fo.y)) * avg_ef;
    s_eab += fg_eab(t, c);
  }
  s_eab += __shfl_xor(s_eab, 1);
  s_eab += __shfl_xor(s_eab, 2);
  if (q) return;
  float deg = (float)((rd1 - rd0) + (rs1 - rs0));
  float mean = s_eab * frcp(deg + 1e-6f);
  float f = 1.0f + mean * avg_nf;
  float p0 = p_n[5 * n], p1 = p_n[5 * n + 1], p2 = p_n[5 * n + 2],
        p3 = p_n[5 * n + 3], p4 = p_n[5 * n + 4];
  float rest = (p1 + p2 + p3 + p4) * f;
  float inv = frcp(p0 + rest);
  p_n[5 * n]     = p0 * inv;
  p_n[5 * n + 1] = p1 * f * inv;
  p_n[5 * n + 2] = p2 * f * inv;
  p_n[5 * n + 3] = p3 * f * inv;
  p_n[5 * n + 4] = p4 * f * inv;
  fgn8[n].y = (int)pack_bf2(nab0, rest * inv);
}

// merged final pass: blocks [0, nodeBlocks) = fg iteration 2 (4 lanes/node,
// writes out_n); blocks [nodeBlocks, ...) = edge output (2 edges/thread).
// Both only READ fgn8.
__global__ void k_fg_final(const int* __restrict__ rowptr_d, const int* __restrict__ dstnbr,
                           const int* __restrict__ rowptr_s, const int* __restrict__ srcnbr,
                           const float* __restrict__ p_n, const int2* __restrict__ fgn8,
                           const float* __restrict__ consts,
                           const int* __restrict__ src, const int* __restrict__ dst,
                           float* __restrict__ out_n, float* __restrict__ out_e,
                           int N, int E, int nodeBlocks) {
  float avg_ef = consts[8], dbec = consts[10];
  if ((int)blockIdx.x < nodeBlocks) {
    int gid = blockIdx.x * blockDim.x + threadIdx.x;
    int n = gid >> 2, q = gid & 3;
    if (n >= N) return;
    float avg_nf = consts[9];
    int2 F = fgn8[n];
    float qv = __uint_as_float((unsigned)F.x);
    float nab0 = bf_lo((unsigned)F.y), nab1 = bf_hi((unsigned)F.y);
    int rd0 = rowptr_d[n], rd1 = (n + 1 < N) ? rowptr_d[n + 1] : E;
    int rs0 = rowptr_s[n], rs1 = (n + 1 < N) ? rowptr_s[n + 1] : E;
    float s_eab = 0.f;
    for (int j = rd0 + q; j < rd1; j += 4) {
      int2 Fo = fgn8[dstnbr[j]];
      float t = 0.5f * (qv + __uint_as_float((unsigned)Fo.x)) + dbec;
      float c = (1.0f + fmaxf(nab0, bf_lo((unsigned)Fo.y)) * avg_ef)
              * (1.0f + fmaxf(nab1, bf_hi((unsigned)Fo.y)) * avg_ef);
      s_eab += fg_eab(t, c);
    }
    for (int j = rs0 + q; j < rs1; j += 4) {
      int2 Fo = fgn8[srcnbr[j]];
      float t = 0.5f * (qv + __uint_as_float((unsigned)Fo.x)) + dbec;
      float c = (1.0f + fmaxf(nab0, bf_lo((unsigned)Fo.y)) * avg_ef)
              * (1.0f + fmaxf(nab1, bf_hi((unsigned)Fo.y)) * avg_ef);
      s_eab += fg_eab(t, c);
    }
    s_eab += __shfl_xor(s_eab, 1);
    s_eab += __shfl_xor(s_eab, 2);
    if (q) return;
    float deg = (float)((rd1 - rd0) + (rs1 - rs0));
    float mean = s_eab * frcp(deg + 1e-6f);
    float f = 1.0f + mean * avg_nf;
    float p0 = p_n[5 * n], p1 = p_n[5 * n + 1], p2 = p_n[5 * n + 2],
          p3 = p_n[5 * n + 3], p4 = p_n[5 * n + 4];
    float rest = (p1 + p2 + p3 + p4) * f;
    float inv = frcp(p0 + rest);
    out_n[5 * n]     = flog(p0 * inv + 1e-9f);
    out_n[5 * n + 1] = flog(p1 * f * inv + 1e-9f);
    out_n[5 * n + 2] = flog(p2 * f * inv + 1e-9f);
    out_n[5 * n + 3] = flog(p3 * f * inv + 1e-9f);
    out_n[5 * n + 4] = flog(p4 * f * inv + 1e-9f);
  } else {
    int e0 = ((blockIdx.x - nodeBlocks) * blockDim.x + threadIdx.x) * 2;
    if (e0 >= E) return;
    int ne = min(2, E - e0);
    int sv[2], dv[2];
#pragma unroll
    for (int u = 0; u < 2; ++u) {
      sv[u] = (u < ne) ? src[e0 + u] : 0;
      dv[u] = (u < ne) ? dst[e0 + u] : 0;
    }
    int2 Fs[2], Fd[2];
#pragma unroll
    for (int u = 0; u < 2; ++u) { Fs[u] = fgn8[sv[u]]; Fd[u] = fgn8[dv[u]]; }
#pragma unroll
    for (int u = 0; u < 2; ++u) {
      if (u >= ne) break;
      float t = 0.5f * (__uint_as_float((unsigned)Fs[u].x) +
                        __uint_as_float((unsigned)Fd[u].x)) + dbec;
      float c = (1.0f + fmaxf(bf_lo((unsigned)Fs[u].y), bf_lo((unsigned)Fd[u].y)) * avg_ef)
              * (1.0f + fmaxf(bf_hi((unsigned)Fs[u].y), bf_hi((unsigned)Fd[u].y)) * avg_ef);
      float ei = fexp(-t);
      float r = frcp(c + ei);
      float pe1 = c * r, pe0 = ei * r;
      *(float2*)&out_e[2 * (e0 + u)] = make_float2(flog(pe0 + 1e-9f), flog(pe1 + 1e-9f));
    }
  }
}

extern "C" void kernel_launch(void* const* d_in, const int* in_sizes, int n_in,
                              void* d_out, int out_size, void* d_ws, size_t ws_size,
                              hipStream_t stream) {
  const float* x      = (const float*)d_in[0];
  const int*   ei     = (const int*)d_in[1];
  const float* eattr  = (const float*)d_in[2];
  const float* W1     = (const float*)d_in[3];
  const float* atts1  = (const float*)d_in[4];
  const float* attd1  = (const float*)d_in[5];
  const float* We1    = (const float*)d_in[6];
  const float* atte1  = (const float*)d_in[7];
  const float* b1     = (const float*)d_in[8];
  const float* W2     = (const float*)d_in[9];
  const float* atts2  = (const float*)d_in[10];
  const float* attd2  = (const float*)d_in[11];
  const float* We2    = (const float*)d_in[12];
  const float* atte2  = (const float*)d_in[13];
  const float* b2     = (const float*)d_in[14];
  const float* Wn     = (const float*)d_in[15];
  const float* bn     = (const float*)d_in[16];
  const float* Wec    = (const float*)d_in[17];
  const float* bec    = (const float*)d_in[18];
  const float* nodefw = (const float*)d_in[19];
  const float* edgefw = (const float*)d_in[20];

  const int N = in_sizes[0] / 128;
  const int E = in_sizes[1] / 2;
  const int* src = ei;
  const int* dst = ei + E;
  const int nbkt = (N + 255) >> BSH;   // 196 (assumes N <= 65536)

  float* out_n = (float*)d_out;
  float* out_e = out_n + (long long)N * 5;

  // ---- workspace carve (f32 units, 16B aligned) ----
  size_t off = 0;
  float* base = (float*)d_ws;
  auto carve = [&](size_t nelem) { float* p = base + off; off += (nelem + 3) & ~(size_t)3; return p; };
  unsigned* h16      = (unsigned*)carve((size_t)N * 64);  // aliases stage_d during prep
  float*    x2       = carve((size_t)N * 64);             // aliases stage_s during prep
  float*    asd      = carve((size_t)N * 4);
  int2*     rec      = (int2*)carve((size_t)E * 2);       // {src, bf16x2 eattr}
  int*      srcnbr   = (int*)carve((size_t)E);
  int*      dstnbr   = (int*)carve((size_t)E);
  int*      rowptr_d = (int*)carve((size_t)N);
  int*      rowptr_s = (int*)carve((size_t)N);
  int*      bktcur_d = (int*)carve(256);
  int*      bktcur_s = (int*)carve(256);
  int*      bktbas_d = (int*)carve(260);
  int*      bktbas_s = (int*)carve(260);
  float*    p_n      = carve((size_t)N * 5);
  int2*     fgn8     = (int2*)carve((size_t)N * 2);
  float*    consts   = carve(16);
  unsigned short* wf1 = (unsigned short*)carve(9216);     // 4*9*512 bf16
  unsigned short* wf2 = (unsigned short*)carve(4608);     // 2*9*512 bf16
  if (off * sizeof(float) > ws_size) return;  // insufficient scratch: fail loudly

  // bucket staging aliases h16/x2 (CSR build completes before they're written):
  int4* stage_d = (int4*)h16;
  int2* stage_s = (int2*)x2;

  const int B = 256;
  const int gE2 = cdiv_i((long long)E, B * 2);   // 2 edges per thread
  const int gN4 = cdiv_i((long long)N * 4, B);   // 4 lanes per node

  // ---- graph prep: merged prep (zeroes cursors) + bucketed CSR build ----
  k_prep<<<1, 256, 0, stream>>>(W1, atts1, attd1, atte1, We1,
                                W2, atts2, attd2, atte2, We2,
                                nodefw, edgefw, bec, consts, wf1, wf2,
                                bktcur_d, bktcur_s);
  k_bkt_hist<<<256, 256, 0, stream>>>(src, dst, bktcur_d, bktcur_s, nbkt, E);
  k_bkt_scan<<<1, 256, 0, stream>>>(bktcur_d, bktbas_d, bktcur_s, bktbas_s, nbkt);
  k_bkt_scatter<<<cdiv_i(E, 256 * CBK), 256, 0, stream>>>(src, dst, eattr, bktcur_d, bktcur_s,
                                                          stage_d, stage_s, nbkt, E);
  k_bkt_sort<<<2 * nbkt, 256, 0, stream>>>(stage_d, bktbas_d, rowptr_d, rec, dstnbr,
                                           stage_s, bktbas_s, rowptr_s, srcnbr, N, nbkt);

  // ---- GAT layer 1 (gemm writes h16+asd; pull writes x2) ----
  k_gemm_att_mfma<128><<<cdiv_i(N, 64), 256, 0, stream>>>(x, wf1, h16, asd, N);
  k_gat_pull<true, false><<<cdiv_i(N, 16), 256, 0, stream>>>(
      rowptr_d, rec, asd, h16, consts, b1,
      nullptr, nullptr, nullptr, x2, nullptr, nullptr, N, E);

  // ---- GAT layer 2 (+ fused heads) ----
  k_gemm_att_mfma<64><<<cdiv_i(N, 64), 256, 0, stream>>>(x2, wf2, h16, asd, N);
  k_gat_pull<false, true><<<cdiv_i(N, 16), 256, 0, stream>>>(
      rowptr_d, rec, asd, h16, consts + 4, b2,
      Wn, bn, Wec, nullptr, p_n, fgn8, N, E);

  // ---- factor graph: iter1 + merged (iter2 + edge output) ----
  k_fg_pull1<<<gN4, B, 0, stream>>>(rowptr_d, dstnbr, rowptr_s, srcnbr,
                                    p_n, fgn8, consts, N, E);
  k_fg_final<<<gN4 + gE2, B, 0, stream>>>(rowptr_d, dstnbr, rowptr_s, srcnbr,
                                          p_n, fgn8, consts, src, dst,
                                          out_n, out_e, N, E, gN4);
}

// Round 16
// 196.738 us; speedup vs baseline: 1.1474x; 1.1474x over previous
//
#include <hip/hip_runtime.h>
#include <math.h>

// GraphRespiratory: 2-layer GAT (edge features, concat=False) + factor graph.
// N=50000, E=800000, IN=128, HID=OUT=64, H=2, NC=5, EC=2, NUM_ITER=2, GAMMA=1.
//
// R15 changes vs R14:
//  - k_prep parallelized to 24 blocks: wext computed cooperatively per block
//    (float4 dots, LDS), consts lane-parallel in block 0, wfrag grid-strided.
//    (Was 1 block with serial scalar loops = 43us at the head of the graph.)
//  - k_gat_pull phase B reverted to the R13 2-deep batch (8-deep raised VGPR
//    and regressed).

static inline int cdiv_i(long long a, long long b) { return (int)((a + b - 1) / b); }

#define BSH 8           // bucket shift: 256 nodes per bucket
#define CBK 8           // edges per thread in bucket scatter (2048/block)

typedef __attribute__((ext_vector_type(8))) short bf16x8s;
typedef __attribute__((ext_vector_type(4))) float f32x4;

__device__ __forceinline__ float fexp(float x) {
  return __builtin_amdgcn_exp2f(x * 1.44269504088896f);
}
__device__ __forceinline__ float flog(float x) {
  return __builtin_amdgcn_logf(x) * 0.693147180559945f;
}
__device__ __forceinline__ float frcp(float x) {
  return __builtin_amdgcn_rcpf(x);
}

__device__ __forceinline__ unsigned short bf16r(float x) {
  unsigned u = __float_as_uint(x);
  return (unsigned short)((u + 0x7fffu + ((u >> 16) & 1u)) >> 16);
}
__device__ __forceinline__ unsigned pack_bf2(float a, float b) {
  unsigned ua = __float_as_uint(a), ub = __float_as_uint(b);
  unsigned ra = (ua + 0x7fffu + ((ua >> 16) & 1u)) >> 16;
  unsigned rb = (ub + 0x7fffu + ((ub >> 16) & 1u)) & 0xffff0000u;
  return ra | rb;
}
__device__ __forceinline__ float bf_lo(unsigned v) { return __uint_as_float(v << 16); }
__device__ __forceinline__ float bf_hi(unsigned v) { return __uint_as_float(v & 0xffff0000u); }

__device__ __forceinline__ float dot64_f4(const float* __restrict__ a,
                                          const float* __restrict__ b) {
  float s = 0.f;
#pragma unroll
  for (int c = 0; c < 64; c += 4) {
    float4 av = *(const float4*)&a[c];
    float4 bv = *(const float4*)&b[c];
    s += av.x * bv.x + av.y * bv.y + av.z * bv.z + av.w * bv.w;
  }
  return s;
}

// Parallel prep (24 blocks): each block computes wext cooperatively (LDS);
// block 0 zeroes cursors + consts (lane-parallel); wfrag grid-strided.
// consts: [0..3] w_e1[h][k], [4..7] w_e2[h][k], [8] avg_ef, [9] avg_nf, [10] dbec
// wf layout: [K/32][9][64 lanes][8 j]; element = W[kc+(lane>>4)*8+j][ct*16+(lane&15)]
__global__ __launch_bounds__(256)
void k_prep(const float* __restrict__ W1, const float* __restrict__ as1,
            const float* __restrict__ ad1, const float* __restrict__ atte1,
            const float* __restrict__ We1,
            const float* __restrict__ W2, const float* __restrict__ as2,
            const float* __restrict__ ad2, const float* __restrict__ atte2,
            const float* __restrict__ We2,
            const float* __restrict__ node_fw, const float* __restrict__ edge_fw,
            const float* __restrict__ bec, float* __restrict__ consts,
            unsigned short* __restrict__ wf1, unsigned short* __restrict__ wf2,
            int* __restrict__ cur_d, int* __restrict__ cur_s) {
  __shared__ float wext1[128 * 4], wext2[64 * 4];
  int t = threadIdx.x;
  // cooperative wext (redundant per block; 3 dots/thread, float4 loads)
  for (int o = t; o < 192 * 4; o += 256) {
    bool l1 = o < 512;
    int oo = l1 ? o : o - 512;
    int k = oo >> 2, j = oo & 3;
    const float* att = l1 ? ((j < 2 ? as1 : ad1) + (j & 1) * 64)
                          : ((j < 2 ? as2 : ad2) + (j & 1) * 64);
    const float* wr = l1 ? (W1 + k * 128 + (j & 1) * 64)
                         : (W2 + k * 128 + (j & 1) * 64);
    float s = dot64_f4(wr, att);
    if (l1) wext1[oo] = s; else wext2[oo] = s;
  }
  if (blockIdx.x == 0) {
    cur_d[t] = 0; cur_s[t] = 0;
    if (t < 8) {
      int layer = t >> 2, h = (t >> 1) & 1, k = t & 1;
      const float* We = layer ? We2 : We1;
      const float* ae = layer ? atte2 : atte1;
      consts[layer * 4 + h * 2 + k] = dot64_f4(&We[k * 128 + h * 64], &ae[h * 64]);
    } else if (t == 8) {
      float ef = 0.f;                  // edge_fw is [EC=2, NC=5]; mean of [1:,1:]
      for (int j = 1; j < 5; ++j) ef += edge_fw[5 + j];
      consts[8] = ef * 0.25f;
    } else if (t == 9) {
      float nf = 0.f;                  // node_fw is [NC=5, EC=2]; mean of [1:,1:]
      for (int i = 1; i < 5; ++i) nf += node_fw[i * 2 + 1];
      consts[9] = nf * 0.25f;
    } else if (t == 10) {
      consts[10] = bec[1] - bec[0];
    }
  }
  __syncthreads();
  const int tot1 = 4 * 9 * 512, tot2 = 2 * 9 * 512;
  for (int o = blockIdx.x * 256 + t; o < tot1; o += gridDim.x * 256) {   // K=128
    int kc = o / (9 * 512), rem = o % (9 * 512);
    int ct = rem / 512, li = rem % 512;
    int lane = li >> 3, j = li & 7;
    int k = kc * 32 + ((lane >> 4) << 3) + j, c = lane & 15;
    float v = (ct < 8) ? W1[k * 128 + ct * 16 + c] : (c < 4 ? wext1[k * 4 + c] : 0.f);
    wf1[o] = bf16r(v);
  }
  for (int o = blockIdx.x * 256 + t; o < tot2; o += gridDim.x * 256) {   // K=64
    int kc = o / (9 * 512), rem = o % (9 * 512);
    int ct = rem / 512, li = rem % 512;
    int lane = li >> 3, j = li & 7;
    int k = kc * 32 + ((lane >> 4) << 3) + j, c = lane & 15;
    float v = (ct < 8) ? W2[k * 128 + ct * 16 + c] : (c < 4 ? wext2[k * 4 + c] : 0.f);
    wf2[o] = bf16r(v);
  }
}

// ---- bucketed CSR build ----
__global__ void k_bkt_hist(const int* __restrict__ src, const int* __restrict__ dst,
                           int* __restrict__ hist_d, int* __restrict__ hist_s,
                           int nbkt, int E) {
  __shared__ int hd[256], hs[256];
  int t = threadIdx.x;
  hd[t] = 0; hs[t] = 0;
  __syncthreads();
  for (int e = blockIdx.x * blockDim.x + t; e < E; e += gridDim.x * blockDim.x) {
    atomicAdd(&hd[dst[e] >> BSH], 1);
    atomicAdd(&hs[src[e] >> BSH], 1);
  }
  __syncthreads();
  if (t < nbkt) {
    if (hd[t]) atomicAdd(&hist_d[t], hd[t]);
    if (hs[t]) atomicAdd(&hist_s[t], hs[t]);
  }
}

// one block: exclusive-scan both histograms -> bases (nbkt+1) and cursors (in place)
__global__ void k_bkt_scan(int* __restrict__ cur_d, int* __restrict__ base_d,
                           int* __restrict__ cur_s, int* __restrict__ base_s, int nbkt) {
  __shared__ int l[256];
  int t = threadIdx.x;
  int v = (t < nbkt) ? cur_d[t] : 0;
  l[t] = v; __syncthreads();
  for (int off = 1; off < 256; off <<= 1) {
    int x = (t >= off) ? l[t - off] : 0; __syncthreads();
    l[t] += x; __syncthreads();
  }
  int incl = l[t];
  if (t < nbkt) { base_d[t] = incl - v; cur_d[t] = incl - v; }
  if (t == nbkt - 1) base_d[nbkt] = incl;
  __syncthreads();
  v = (t < nbkt) ? cur_s[t] : 0;
  l[t] = v; __syncthreads();
  for (int off = 1; off < 256; off <<= 1) {
    int x = (t >= off) ? l[t - off] : 0; __syncthreads();
    l[t] += x; __syncthreads();
  }
  incl = l[t];
  if (t < nbkt) { base_s[t] = incl - v; cur_s[t] = incl - v; }
  if (t == nbkt - 1) base_s[nbkt] = incl;
}

// block-staged bucket scatter: 2048 edges/block in regs; LDS per-bucket counts;
// one global atomicAdd per (bucket,block) to reserve; chunky tail writes.
__global__ __launch_bounds__(256)
void k_bkt_scatter(const int* __restrict__ src, const int* __restrict__ dst,
                   const float* __restrict__ eattr2,
                   int* __restrict__ cur_d, int* __restrict__ cur_s,
                   int4* __restrict__ stage_d, int2* __restrict__ stage_s,
                   int nbkt, int E) {
  __shared__ int cd[256], cs[256], bd[256], bs[256];
  int t = threadIdx.x;
  cd[t] = 0; cs[t] = 0;
  __syncthreads();
  int base = blockIdx.x * 256 * CBK;
  int s[CBK], d[CBK]; unsigned ep[CBK];
#pragma unroll
  for (int c = 0; c < CBK; ++c) {
    int e = base + c * 256 + t;
    if (e < E) {
      s[c] = src[e]; d[c] = dst[e];
      float2 ev = *(const float2*)&eattr2[2 * e];
      ep[c] = pack_bf2(ev.x, ev.y);
      atomicAdd(&cd[d[c] >> BSH], 1);
      atomicAdd(&cs[s[c] >> BSH], 1);
    } else s[c] = -1;
  }
  __syncthreads();
  if (t < nbkt) {
    bd[t] = cd[t] ? atomicAdd(&cur_d[t], cd[t]) : 0;
    bs[t] = cs[t] ? atomicAdd(&cur_s[t], cs[t]) : 0;
    cd[t] = 0; cs[t] = 0;
  }
  __syncthreads();
#pragma unroll
  for (int c = 0; c < CBK; ++c) {
    if (s[c] < 0) continue;
    int db = d[c] >> BSH, sb = s[c] >> BSH;
    int pos = bd[db] + atomicAdd(&cd[db], 1);
    stage_d[pos] = make_int4(s[c], d[c], (int)ep[c], 0);
    int pos2 = bs[sb] + atomicAdd(&cs[sb], 1);
    stage_s[pos2] = make_int2(s[c], d[c]);
  }
}

// merged per-bucket counting sorts: blocks [0,nbkt) dst side, [nbkt,2nbkt) src.
// dst side also emits dstnbr (src-id only, dense 4B) for the fg kernels.
__global__ __launch_bounds__(256)
void k_bkt_sort(const int4* __restrict__ stage_d, const int* __restrict__ base_d,
                int* __restrict__ rowptr_d, int2* __restrict__ rec,
                int* __restrict__ dstnbr,
                const int2* __restrict__ stage_s, const int* __restrict__ base_s,
                int* __restrict__ rowptr_s, int* __restrict__ srcnbr,
                int N, int nbkt) {
  int t = threadIdx.x;
  __shared__ int cnt[256], cur[256], l[256];
  if ((int)blockIdx.x < nbkt) {
    int b = blockIdx.x;
    int nlo = b << BSH;
    int b0 = base_d[b], b1 = base_d[b + 1];
    cnt[t] = 0;
    __syncthreads();
    for (int j = b0 + t; j < b1; j += 256)
      atomicAdd(&cnt[stage_d[j].y - nlo], 1);
    __syncthreads();
    int v = cnt[t];
    l[t] = v; __syncthreads();
    for (int off = 1; off < 256; off <<= 1) {
      int x = (t >= off) ? l[t - off] : 0; __syncthreads();
      l[t] += x; __syncthreads();
    }
    int excl = l[t] - v;
    if (nlo + t < N) rowptr_d[nlo + t] = b0 + excl;
    cur[t] = excl;
    __syncthreads();
    for (int j = b0 + t; j < b1; j += 256) {
      int4 r = stage_d[j];
      int pos = b0 + atomicAdd(&cur[r.y - nlo], 1);
      rec[pos] = make_int2(r.x, r.z);
      dstnbr[pos] = r.x;
    }
  } else {
    int b = blockIdx.x - nbkt;
    int nlo = b << BSH;
    int b0 = base_s[b], b1 = base_s[b + 1];
    cnt[t] = 0;
    __syncthreads();
    for (int j = b0 + t; j < b1; j += 256)
      atomicAdd(&cnt[stage_s[j].x - nlo], 1);
    __syncthreads();
    int v = cnt[t];
    l[t] = v; __syncthreads();
    for (int off = 1; off < 256; off <<= 1) {
      int x = (t >= off) ? l[t - off] : 0; __syncthreads();
      l[t] += x; __syncthreads();
    }
    int excl = l[t] - v;
    if (nlo + t < N) rowptr_s[nlo + t] = b0 + excl;
    cur[t] = excl;
    __syncthreads();
    for (int j = b0 + t; j < b1; j += 256) {
      int2 r = stage_s[j];
      int pos = b0 + atomicAdd(&cur[r.x - nlo], 1);
      srcnbr[pos] = r.y;
    }
  }
}

// MFMA GEMM + attention columns. A[N][K] f32 -> bf16 in-reg; Wf pre-swizzled
// B-fragments (9 col-tiles: 8 of W + 1 of wext). Block = 4 waves x 16 rows.
template<int K>
__global__ __launch_bounds__(256)
void k_gemm_att_mfma(const float* __restrict__ A, const unsigned short* __restrict__ Wf,
                     unsigned* __restrict__ h16, float* __restrict__ asd, int N) {
  int wv = threadIdx.x >> 6, lane = threadIdx.x & 63;
  int r0 = blockIdx.x * 64 + wv * 16;
  int arow = r0 + (lane & 15);
  int kbase = (lane >> 4) * 8;
  f32x4 acc[9];
#pragma unroll
  for (int ct = 0; ct < 9; ++ct) acc[ct] = (f32x4){0.f, 0.f, 0.f, 0.f};

#pragma unroll
  for (int kc = 0; kc < K; kc += 32) {
    float4 v0 = make_float4(0.f, 0.f, 0.f, 0.f);
    float4 v1 = make_float4(0.f, 0.f, 0.f, 0.f);
    if (arow < N) {
      const float* ap = A + (long long)arow * K + kc + kbase;
      v0 = *(const float4*)ap;
      v1 = *(const float4*)(ap + 4);
    }
    bf16x8s a;
    a[0] = (short)bf16r(v0.x); a[1] = (short)bf16r(v0.y);
    a[2] = (short)bf16r(v0.z); a[3] = (short)bf16r(v0.w);
    a[4] = (short)bf16r(v1.x); a[5] = (short)bf16r(v1.y);
    a[6] = (short)bf16r(v1.z); a[7] = (short)bf16r(v1.w);
    const unsigned short* wp = Wf + (size_t)(kc >> 5) * 9 * 512 + lane * 8;
#pragma unroll
    for (int ct = 0; ct < 9; ++ct) {
      bf16x8s b = *(const bf16x8s*)(wp + ct * 512);
      acc[ct] = __builtin_amdgcn_mfma_f32_16x16x32_bf16(a, b, acc[ct], 0, 0, 0);
    }
  }
  // D layout: col = lane&15, row = (lane>>4)*4 + reg
  int c = lane & 15;
  int orow = r0 + (lane >> 4) * 4;
#pragma unroll
  for (int r = 0; r < 4; ++r) {
    int gr = orow + r;
    if (gr >= N) continue;
#pragma unroll
    for (int ct = 0; ct < 4; ++ct)
      h16[((long long)gr << 6) | (ct * 16 + c)] = pack_bf2(acc[ct][r], acc[ct + 4][r]);
    if (c < 4) asd[gr * 4 + c] = acc[8][r];
  }
}

// Fused GAT edge phase, pull-mode. ONE 16-LANE GROUP PER DST NODE (4/wave).
template<bool RELU, bool HEAD>
__global__ __launch_bounds__(256)
void k_gat_pull(const int* __restrict__ rowptr, const int2* __restrict__ rec,
                const float* __restrict__ asd, const unsigned* __restrict__ h16,
                const float* __restrict__ we, const float* __restrict__ bias,
                const float* __restrict__ Wn, const float* __restrict__ bn,
                const float* __restrict__ Wec,
                float* __restrict__ out, float* __restrict__ p_n,
                int2* __restrict__ fgn8, int N, int E) {
  __shared__ int2 ed[4][64];
  int wv = threadIdx.x >> 6, lane = threadIdx.x & 63;
  int g = lane >> 4;        // group (node) within wave
  int tl = lane & 15;       // lane within group = col-quad index
  int d = blockIdx.x * 16 + wv * 4 + g;
  if (d >= N) return;       // whole group exits together (shfl stays in-group)
  int r0 = rowptr[d];
  int r1 = (d + 1 < N) ? rowptr[d + 1] : E;
  int deg = r1 - r0;
  float4 Ad = *(const float4*)&asd[4 * d];
  float w0 = we[0], w1 = we[1], w2 = we[2], w3 = we[3];
  float den0 = 0.f, den1 = 0.f, se0 = 0.f, se1 = 0.f;
  float accA[4] = {0.f, 0.f, 0.f, 0.f}, accB[4] = {0.f, 0.f, 0.f, 0.f};
  int2* edg = &ed[wv][g << 4];
  for (int cb = 0; cb < deg; cb += 16) {
    int j = cb + tl;
    int s = 0; unsigned eapk = 0;
    if (j < deg) {
      int2 rc = rec[r0 + j];
      s = rc.x;
      unsigned ep = (unsigned)rc.y;
      float e0 = bf_lo(ep), e1 = bf_hi(ep);
      float4 As = *(const float4*)&asd[4 * s];
      float x0 = As.x + Ad.z + e0 * w0 + e1 * w1;
      float x1 = As.y + Ad.w + e0 * w2 + e1 * w3;
      x0 = x0 >= 0.f ? x0 : 0.2f * x0;
      x1 = x1 >= 0.f ? x1 : 0.2f * x1;
      float ea0 = fexp(x0), ea1 = fexp(x1);
      eapk = pack_bf2(ea0, ea1);
      den0 += ea0; den1 += ea1; se0 += e0; se1 += e1;
    }
    edg[tl] = make_int2(s, (int)eapk);   // same-wave LDS: no barrier needed
    int m = min(16, deg - cb);
    int j2 = 0;
    for (; j2 + 2 <= m; j2 += 2) {       // 2 edges in flight
      int2 va = edg[j2];
      int2 vb = edg[j2 + 1];
      uint4 qa = *(const uint4*)&h16[((long long)va.x << 6) | (tl << 2)];
      uint4 qb = *(const uint4*)&h16[((long long)vb.x << 6) | (tl << 2)];
      float a0 = bf_lo((unsigned)va.y), a1 = bf_hi((unsigned)va.y);
      float b0 = bf_lo((unsigned)vb.y), b1 = bf_hi((unsigned)vb.y);
      accA[0] += a0 * bf_lo(qa.x); accB[0] += a1 * bf_hi(qa.x);
      accA[1] += a0 * bf_lo(qa.y); accB[1] += a1 * bf_hi(qa.y);
      accA[2] += a0 * bf_lo(qa.z); accB[2] += a1 * bf_hi(qa.z);
      accA[3] += a0 * bf_lo(qa.w); accB[3] += a1 * bf_hi(qa.w);
      accA[0] += b0 * bf_lo(qb.x); accB[0] += b1 * bf_hi(qb.x);
      accA[1] += b0 * bf_lo(qb.y); accB[1] += b1 * bf_hi(qb.y);
      accA[2] += b0 * bf_lo(qb.z); accB[2] += b1 * bf_hi(qb.z);
      accA[3] += b0 * bf_lo(qb.w); accB[3] += b1 * bf_hi(qb.w);
    }
    if (j2 < m) {
      int2 va = edg[j2];
      uint4 qa = *(const uint4*)&h16[((long long)va.x << 6) | (tl << 2)];
      float a0 = bf_lo((unsigned)va.y), a1 = bf_hi((unsigned)va.y);
      accA[0] += a0 * bf_lo(qa.x); accB[0] += a1 * bf_hi(qa.x);
      accA[1] += a0 * bf_lo(qa.y); accB[1] += a1 * bf_hi(qa.y);
      accA[2] += a0 * bf_lo(qa.z); accB[2] += a1 * bf_hi(qa.z);
      accA[3] += a0 * bf_lo(qa.w); accB[3] += a1 * bf_hi(qa.w);
    }
  }
  // reduce den/se within the 16-lane group
  for (int off = 8; off; off >>= 1) {
    den0 += __shfl_xor(den0, off); den1 += __shfl_xor(den1, off);
    se0  += __shfl_xor(se0, off);  se1  += __shfl_xor(se1, off);
  }
  // self-loop (identical on all 16 lanes)
  float id = frcp(fmaxf((float)deg, 1.0f));
  float le0 = se0 * id, le1 = se1 * id;
  float x0 = Ad.x + Ad.z + le0 * w0 + le1 * w1;
  float x1 = Ad.y + Ad.w + le0 * w2 + le1 * w3;
  x0 = x0 >= 0.f ? x0 : 0.2f * x0;
  x1 = x1 >= 0.f ? x1 : 0.2f * x1;
  float eas0 = fexp(x0), eas1 = fexp(x1);
  den0 += eas0; den1 += eas1;
  uint4 qd = *(const uint4*)&h16[((long long)d << 6) | (tl << 2)];
  accA[0] += eas0 * bf_lo(qd.x); accB[0] += eas1 * bf_hi(qd.x);
  accA[1] += eas0 * bf_lo(qd.y); accB[1] += eas1 * bf_hi(qd.y);
  accA[2] += eas0 * bf_lo(qd.z); accB[2] += eas1 * bf_hi(qd.z);
  accA[3] += eas0 * bf_lo(qd.w); accB[3] += eas1 * bf_hi(qd.w);
  float rcp0 = frcp(den0 + 1e-16f), rcp1 = frcp(den1 + 1e-16f);
  float4 bs = *(const float4*)&bias[tl << 2];
  float v0 = 0.5f * (accA[0] * rcp0 + accB[0] * rcp1) + bs.x;
  float v1 = 0.5f * (accA[1] * rcp0 + accB[1] * rcp1) + bs.y;
  float v2 = 0.5f * (accA[2] * rcp0 + accB[2] * rcp1) + bs.z;
  float v3 = 0.5f * (accA[3] * rcp0 + accB[3] * rcp1) + bs.w;
  if (HEAD) {
    int c0 = tl << 2;
    float pv[7];
#pragma unroll
    for (int j = 0; j < 5; ++j)
      pv[j] = v0 * Wn[c0 * 5 + j] + v1 * Wn[(c0 + 1) * 5 + j]
            + v2 * Wn[(c0 + 2) * 5 + j] + v3 * Wn[(c0 + 3) * 5 + j];
    pv[5] = v0 * Wec[c0 * 2] + v1 * Wec[(c0 + 1) * 2]
          + v2 * Wec[(c0 + 2) * 2] + v3 * Wec[(c0 + 3) * 2];
    pv[6] = v0 * Wec[c0 * 2 + 1] + v1 * Wec[(c0 + 1) * 2 + 1]
          + v2 * Wec[(c0 + 2) * 2 + 1] + v3 * Wec[(c0 + 3) * 2 + 1];
    for (int off = 8; off; off >>= 1) {
#pragma unroll
      for (int j = 0; j < 7; ++j) pv[j] += __shfl_xor(pv[j], off);
    }
    if (tl == 0) {
      float l[5]; float m = -1e30f;
#pragma unroll
      for (int j = 0; j < 5; ++j) { l[j] = pv[j] + bn[j]; m = fmaxf(m, l[j]); }
      float ssum = 0.f;
#pragma unroll
      for (int j = 0; j < 5; ++j) { l[j] = fexp(l[j] - m); ssum += l[j]; }
      float inv = frcp(ssum);
#pragma unroll
      for (int j = 0; j < 5; ++j) p_n[5 * d + j] = l[j] * inv;
      float nab0 = (ssum - l[0]) * inv;
      fgn8[d] = make_int2(__float_as_int(pv[6] - pv[5]), (int)pack_bf2(nab0, 0.f));
    }
  } else {
    if (RELU) {
      v0 = fmaxf(v0, 0.f); v1 = fmaxf(v1, 0.f);
      v2 = fmaxf(v2, 0.f); v3 = fmaxf(v3, 0.f);
    }
    *(float4*)&out[(long long)d * 64 + (tl << 2)] = make_float4(v0, v1, v2, v3);
  }
}

// eab = c / (c + exp(-t)) : one rcp, shared structure.
__device__ __forceinline__ float fg_eab(float t, float c) {
  return c * frcp(c + fexp(-t));
}

// factor-graph node-pull iteration 1. FOUR LANES PER NODE (stride-4 edge split).
__global__ void k_fg_pull1(const int* __restrict__ rowptr_d, const int* __restrict__ dstnbr,
                           const int* __restrict__ rowptr_s, const int* __restrict__ srcnbr,
                           float* __restrict__ p_n, int2* __restrict__ fgn8,
                           const float* __restrict__ consts, int N, int E) {
  int gid = blockIdx.x * blockDim.x + threadIdx.x;
  int n = gid >> 2, q = gid & 3;
  if (n >= N) return;
  int2 F = fgn8[n];
  float qv = __uint_as_float((unsigned)F.x);
  float nab0 = bf_lo((unsigned)F.y);
  float avg_ef = consts[8], avg_nf = consts[9], dbec = consts[10];
  int rd0 = rowptr_d[n], rd1 = (n + 1 < N) ? rowptr_d[n + 1] : E;
  int rs0 = rowptr_s[n], rs1 = (n + 1 < N) ? rowptr_s[n + 1] : E;
  float s_eab = 0.f;
  for (int j = rd0 + q; j < rd1; j += 4) {
    int2 Fo = fgn8[dstnbr[j]];
    float t = 0.5f * (qv + __uint_as_float((unsigned)Fo.x)) + dbec;
    float c = 1.0f + fmaxf(nab0, bf_lo((unsigned)Fo.y)) * avg_ef;
    s_eab += fg_eab(t, c);
  }
  for (int j = rs0 + q; j < rs1; j += 4) {
    int2 Fo = fgn8[srcnbr[j]];
    float t = 0.5f * (qv + __uint_as_float((unsigned)Fo.x)) + dbec;
    float c = 1.0f + fmaxf(nab0, bf_lo((unsigned)Fo.y)) * avg_ef;
    s_eab += fg_eab(t, c);
  }
  s_eab += __shfl_xor(s_eab, 1);
  s_eab += __shfl_xor(s_eab, 2);
  if (q) return;
  float deg = (float)((rd1 - rd0) + (rs1 - rs0));
  float mean = s_eab * frcp(deg + 1e-6f);
  float f = 1.0f + mean * avg_nf;
  float p0 = p_n[5 * n], p1 = p_n[5 * n + 1], p2 = p_n[5 * n + 2],
        p3 = p_n[5 * n + 3], p4 = p_n[5 * n + 4];
  float rest = (p1 + p2 + p3 + p4) * f;
  float inv = frcp(p0 + rest);
  p_n[5 * n]     = p0 * inv;
  p_n[5 * n + 1] = p1 * f * inv;
  p_n[5 * n + 2] = p2 * f * inv;
  p_n[5 * n + 3] = p3 * f * inv;
  p_n[5 * n + 4] = p4 * f * inv;
  fgn8[n].y = (int)pack_bf2(nab0, rest * inv);
}

// merged final pass: blocks [0, nodeBlocks) = fg iteration 2 (4 lanes/node,
// writes out_n); blocks [nodeBlocks, ...) = edge output (2 edges/thread).
// Both only READ fgn8.
__global__ void k_fg_final(const int* __restrict__ rowptr_d, const int* __restrict__ dstnbr,
                           const int* __restrict__ rowptr_s, const int* __restrict__ srcnbr,
                           const float* __restrict__ p_n, const int2* __restrict__ fgn8,
                           const float* __restrict__ consts,
                           const int* __restrict__ src, const int* __restrict__ dst,
                           float* __restrict__ out_n, float* __restrict__ out_e,
                           int N, int E, int nodeBlocks) {
  float avg_ef = consts[8], dbec = consts[10];
  if ((int)blockIdx.x < nodeBlocks) {
    int gid = blockIdx.x * blockDim.x + threadIdx.x;
    int n = gid >> 2, q = gid & 3;
    if (n >= N) return;
    float avg_nf = consts[9];
    int2 F = fgn8[n];
    float qv = __uint_as_float((unsigned)F.x);
    float nab0 = bf_lo((unsigned)F.y), nab1 = bf_hi((unsigned)F.y);
    int rd0 = rowptr_d[n], rd1 = (n + 1 < N) ? rowptr_d[n + 1] : E;
    int rs0 = rowptr_s[n], rs1 = (n + 1 < N) ? rowptr_s[n + 1] : E;
    float s_eab = 0.f;
    for (int j = rd0 + q; j < rd1; j += 4) {
      int2 Fo = fgn8[dstnbr[j]];
      float t = 0.5f * (qv + __uint_as_float((unsigned)Fo.x)) + dbec;
      float c = (1.0f + fmaxf(nab0, bf_lo((unsigned)Fo.y)) * avg_ef)
              * (1.0f + fmaxf(nab1, bf_hi((unsigned)Fo.y)) * avg_ef);
      s_eab += fg_eab(t, c);
    }
    for (int j = rs0 + q; j < rs1; j += 4) {
      int2 Fo = fgn8[srcnbr[j]];
      float t = 0.5f * (qv + __uint_as_float((unsigned)Fo.x)) + dbec;
      float c = (1.0f + fmaxf(nab0, bf_lo((unsigned)Fo.y)) * avg_ef)
              * (1.0f + fmaxf(nab1, bf_hi((unsigned)Fo.y)) * avg_ef);
      s_eab += fg_eab(t, c);
    }
    s_eab += __shfl_xor(s_eab, 1);
    s_eab += __shfl_xor(s_eab, 2);
    if (q) return;
    float deg = (float)((rd1 - rd0) + (rs1 - rs0));
    float mean = s_eab * frcp(deg + 1e-6f);
    float f = 1.0f + mean * avg_nf;
    float p0 = p_n[5 * n], p1 = p_n[5 * n + 1], p2 = p_n[5 * n + 2],
          p3 = p_n[5 * n + 3], p4 = p_n[5 * n + 4];
    float rest = (p1 + p2 + p3 + p4) * f;
    float inv = frcp(p0 + rest);
    out_n[5 * n]     = flog(p0 * inv + 1e-9f);
    out_n[5 * n + 1] = flog(p1 * f * inv + 1e-9f);
    out_n[5 * n + 2] = flog(p2 * f * inv + 1e-9f);
    out_n[5 * n + 3] = flog(p3 * f * inv + 1e-9f);
    out_n[5 * n + 4] = flog(p4 * f * inv + 1e-9f);
  } else {
    int e0 = ((blockIdx.x - nodeBlocks) * blockDim.x + threadIdx.x) * 2;
    if (e0 >= E) return;
    int ne = min(2, E - e0);
    int sv[2], dv[2];
#pragma unroll
    for (int u = 0; u < 2; ++u) {
      sv[u] = (u < ne) ? src[e0 + u] : 0;
      dv[u] = (u < ne) ? dst[e0 + u] : 0;
    }
    int2 Fs[2], Fd[2];
#pragma unroll
    for (int u = 0; u < 2; ++u) { Fs[u] = fgn8[sv[u]]; Fd[u] = fgn8[dv[u]]; }
#pragma unroll
    for (int u = 0; u < 2; ++u) {
      if (u >= ne) break;
      float t = 0.5f * (__uint_as_float((unsigned)Fs[u].x) +
                        __uint_as_float((unsigned)Fd[u].x)) + dbec;
      float c = (1.0f + fmaxf(bf_lo((unsigned)Fs[u].y), bf_lo((unsigned)Fd[u].y)) * avg_ef)
              * (1.0f + fmaxf(bf_hi((unsigned)Fs[u].y), bf_hi((unsigned)Fd[u].y)) * avg_ef);
      float ei = fexp(-t);
      float r = frcp(c + ei);
      float pe1 = c * r, pe0 = ei * r;
      *(float2*)&out_e[2 * (e0 + u)] = make_float2(flog(pe0 + 1e-9f), flog(pe1 + 1e-9f));
    }
  }
}

extern "C" void kernel_launch(void* const* d_in, const int* in_sizes, int n_in,
                              void* d_out, int out_size, void* d_ws, size_t ws_size,
                              hipStream_t stream) {
  const float* x      = (const float*)d_in[0];
  const int*   ei     = (const int*)d_in[1];
  const float* eattr  = (const float*)d_in[2];
  const float* W1     = (const float*)d_in[3];
  const float* atts1  = (const float*)d_in[4];
  const float* attd1  = (const float*)d_in[5];
  const float* We1    = (const float*)d_in[6];
  const float* atte1  = (const float*)d_in[7];
  const float* b1     = (const float*)d_in[8];
  const float* W2     = (const float*)d_in[9];
  const float* atts2  = (const float*)d_in[10];
  const float* attd2  = (const float*)d_in[11];
  const float* We2    = (const float*)d_in[12];
  const float* atte2  = (const float*)d_in[13];
  const float* b2     = (const float*)d_in[14];
  const float* Wn     = (const float*)d_in[15];
  const float* bn     = (const float*)d_in[16];
  const float* Wec    = (const float*)d_in[17];
  const float* bec    = (const float*)d_in[18];
  const float* nodefw = (const float*)d_in[19];
  const float* edgefw = (const float*)d_in[20];

  const int N = in_sizes[0] / 128;
  const int E = in_sizes[1] / 2;
  const int* src = ei;
  const int* dst = ei + E;
  const int nbkt = (N + 255) >> BSH;   // 196 (assumes N <= 65536)

  float* out_n = (float*)d_out;
  float* out_e = out_n + (long long)N * 5;

  // ---- workspace carve (f32 units, 16B aligned) ----
  size_t off = 0;
  float* base = (float*)d_ws;
  auto carve = [&](size_t nelem) { float* p = base + off; off += (nelem + 3) & ~(size_t)3; return p; };
  unsigned* h16      = (unsigned*)carve((size_t)N * 64);  // aliases stage_d during prep
  float*    x2       = carve((size_t)N * 64);             // aliases stage_s during prep
  float*    asd      = carve((size_t)N * 4);
  int2*     rec      = (int2*)carve((size_t)E * 2);       // {src, bf16x2 eattr}
  int*      srcnbr   = (int*)carve((size_t)E);
  int*      dstnbr   = (int*)carve((size_t)E);
  int*      rowptr_d = (int*)carve((size_t)N);
  int*      rowptr_s = (int*)carve((size_t)N);
  int*      bktcur_d = (int*)carve(256);
  int*      bktcur_s = (int*)carve(256);
  int*      bktbas_d = (int*)carve(260);
  int*      bktbas_s = (int*)carve(260);
  float*    p_n      = carve((size_t)N * 5);
  int2*     fgn8     = (int2*)carve((size_t)N * 2);
  float*    consts   = carve(16);
  unsigned short* wf1 = (unsigned short*)carve(9216);     // 4*9*512 bf16
  unsigned short* wf2 = (unsigned short*)carve(4608);     // 2*9*512 bf16
  if (off * sizeof(float) > ws_size) return;  // insufficient scratch: fail loudly

  // bucket staging aliases h16/x2 (CSR build completes before they're written):
  int4* stage_d = (int4*)h16;
  int2* stage_s = (int2*)x2;

  const int B = 256;
  const int gE2 = cdiv_i((long long)E, B * 2);   // 2 edges per thread
  const int gN4 = cdiv_i((long long)N * 4, B);   // 4 lanes per node

  // ---- graph prep: parallel prep (zeroes cursors) + bucketed CSR build ----
  k_prep<<<24, 256, 0, stream>>>(W1, atts1, attd1, atte1, We1,
                                 W2, atts2, attd2, atte2, We2,
                                 nodefw, edgefw, bec, consts, wf1, wf2,
                                 bktcur_d, bktcur_s);
  k_bkt_hist<<<256, 256, 0, stream>>>(src, dst, bktcur_d, bktcur_s, nbkt, E);
  k_bkt_scan<<<1, 256, 0, stream>>>(bktcur_d, bktbas_d, bktcur_s, bktbas_s, nbkt);
  k_bkt_scatter<<<cdiv_i(E, 256 * CBK), 256, 0, stream>>>(src, dst, eattr, bktcur_d, bktcur_s,
                                                          stage_d, stage_s, nbkt, E);
  k_bkt_sort<<<2 * nbkt, 256, 0, stream>>>(stage_d, bktbas_d, rowptr_d, rec, dstnbr,
                                           stage_s, bktbas_s, rowptr_s, srcnbr, N, nbkt);

  // ---- GAT layer 1 (gemm writes h16+asd; pull writes x2) ----
  k_gemm_att_mfma<128><<<cdiv_i(N, 64), 256, 0, stream>>>(x, wf1, h16, asd, N);
  k_gat_pull<true, false><<<cdiv_i(N, 16), 256, 0, stream>>>(
      rowptr_d, rec, asd, h16, consts, b1,
      nullptr, nullptr, nullptr, x2, nullptr, nullptr, N, E);

  // ---- GAT layer 2 (+ fused heads) ----
  k_gemm_att_mfma<64><<<cdiv_i(N, 64), 256, 0, stream>>>(x2, wf2, h16, asd, N);
  k_gat_pull<false, true><<<cdiv_i(N, 16), 256, 0, stream>>>(
      rowptr_d, rec, asd, h16, consts + 4, b2,
      Wn, bn, Wec, nullptr, p_n, fgn8, N, E);

  // ---- factor graph: iter1 + merged (iter2 + edge output) ----
  k_fg_pull1<<<gN4, B, 0, stream>>>(rowptr_d, dstnbr, rowptr_s, srcnbr,
                                    p_n, fgn8, consts, N, E);
  k_fg_final<<<gN4 + gE2, B, 0, stream>>>(rowptr_d, dstnbr, rowptr_s, srcnbr,
                                          p_n, fgn8, consts, src, dst,
                                          out_n, out_e, N, E, gN4);
}